// Round 7
// baseline (132.955 us; speedup 1.0000x reference)
//
#include <hip/hip_runtime.h>

constexpr int Bn = 128, Vn = 256, Fn = 64;
constexpr int NSLR = 68, NSn = 4, NLRn = 64;
constexpr int Kn = 40, NOUTn = 128;
constexpr int ROWS = Bn * Vn;  // 32768
constexpr int KB2 = 192;       // GEMM2 K (x 64 | ftm 64 | ftx 64)

typedef __attribute__((ext_vector_type(8))) short short8;
typedef __attribute__((ext_vector_type(4))) float f32x4;

__device__ __forceinline__ int mbcnt64(unsigned long long m) {
  return __builtin_amdgcn_mbcnt_hi((unsigned)(m >> 32),
         __builtin_amdgcn_mbcnt_lo((unsigned)(m & 0xFFFFFFFFull), 0));
}
__device__ __forceinline__ unsigned short rneb(float v) {  // fp32 -> bf16 RNE
  unsigned u = __float_as_uint(v);
  unsigned r = u + 0x7FFFu + ((u >> 16) & 1u);
  return (unsigned short)(r >> 16);
}
__device__ __forceinline__ float bf2f(unsigned short h) {
  return __uint_as_float(((unsigned)h) << 16);
}
#define GL_LDS(gp, lp) __builtin_amdgcn_global_load_lds( \
    (const __attribute__((address_space(1))) void*)(gp), \
    (__attribute__((address_space(3))) void*)(lp), 16, 0, 0)

// ---- K0: all prep. blocks 0..127: x split + xmean + bias1/bias2 (per b).
//          blocks 128..255: W transpose/split. ----
__global__ __launch_bounds__(256) void kprep(
    const float* __restrict__ x,
    const float* __restrict__ W_slr, const float* __restrict__ b_slr,
    const float* __restrict__ W_out, const float* __restrict__ b_out,
    short* __restrict__ xhi, short* __restrict__ xlo,
    short* __restrict__ wt1h, short* __restrict__ wt1l, short* __restrict__ wt2,
    float* __restrict__ bias1, float* __restrict__ bias2) {
  const int blk = blockIdx.x, t = threadIdx.x;
  if (blk >= Bn) {  // ---- W prep ----
    const int col = blk - Bn;  // 0..127
    if (t < 64) {
      float val = (col < NSLR) ? W_slr[t * NSLR + col] : 0.f;
      unsigned short h = rneb(val);
      wt1h[col * 64 + t] = (short)h;
      wt1l[col * 64 + t] = (short)rneb(val - bf2f(h));
    } else {
      int k = t - 64;                   // 0..191
      int row = (k < 64) ? k : 64 + k;  // skip xmean rows 64..127
      wt2[col * KB2 + k] = (short)rneb(W_out[row * NOUTn + col]);
    }
    return;
  }
  // ---- x prep for b = blk ----
  const int b = blk;
  const int f4 = t & 15, vg = t >> 4;
  const float4* xb = (const float4*)(x + (size_t)b * 16384);
  float4 sum = make_float4(0.f, 0.f, 0.f, 0.f);
  for (int i = 0; i < 16; ++i) {
    int v = vg * 16 + i;
    float4 val = xb[v * 16 + f4];
    sum.x += val.x; sum.y += val.y; sum.z += val.z; sum.w += val.w;
    unsigned short h0 = rneb(val.x), h1 = rneb(val.y), h2 = rneb(val.z), h3 = rneb(val.w);
    short4 hi = {(short)h0, (short)h1, (short)h2, (short)h3};
    short4 lo = {(short)rneb(val.x - bf2f(h0)), (short)rneb(val.y - bf2f(h1)),
                 (short)rneb(val.z - bf2f(h2)), (short)rneb(val.w - bf2f(h3))};
    size_t o = (size_t)b * 4096 + v * 16 + f4;
    ((short4*)xhi)[o] = hi;
    ((short4*)xlo)[o] = lo;
  }
  __shared__ float4 ps[16][16];
  __shared__ float xms[64];
  ps[vg][f4] = sum;
  __syncthreads();
  if (t < 16) {
    float4 m = ps[0][t];
    for (int g = 1; g < 16; ++g) {
      float4 v = ps[g][t];
      m.x += v.x; m.y += v.y; m.z += v.z; m.w += v.w;
    }
    m.x *= (1.f / 256.f); m.y *= (1.f / 256.f); m.z *= (1.f / 256.f); m.w *= (1.f / 256.f);
    ((float4*)xms)[t] = m;
  }
  __syncthreads();
  if (t < 128) {
    float acc = b_out[t];
    for (int f = 0; f < 64; ++f) acc = fmaf(xms[f], W_out[(64 + f) * NOUTn + t], acc);
    bias2[b * 128 + t] = acc;
  } else {
    int c = t - 128;
    if (c < NSLR) {
      float acc = b_slr[c];
      for (int f = 0; f < 64; ++f) acc = fmaf(xms[f], W_slr[(64 + f) * NSLR + c], acc);
      bias1[b * 128 + c] = acc;
    }
  }
}

// ---- GEMM1: K=64, tile 64x128, 4 waves. 3-pass hi/lo for the s-fragment only;
//      lr single-pass bf16, emitted as bf16 u16. ----
__global__ __launch_bounds__(256) void kgemm1(
    const short* __restrict__ xhi, const short* __restrict__ xlo,
    const short* __restrict__ wt1h, const short* __restrict__ wt1l,
    const float* __restrict__ bias1,
    float* __restrict__ s_ws, unsigned short* __restrict__ lr_bf) {
  __shared__ __align__(16) short Ah[4096], Al[4096], Bh[8192], Bl[1024];
  const int t = threadIdx.x, l = t & 63, w = t >> 6;
  const int wr = w >> 1, wc = w & 1;
  const int rowBase = blockIdx.x * 64;
  const int b = rowBase >> 8;
  const int lr8 = l >> 3, ul = (l & 7) ^ lr8;

#pragma unroll
  for (int rep = 0; rep < 2; ++rep) {
    const int seg = w + rep * 4;  // 0..7
    size_t o = (size_t)(rowBase + seg * 8 + lr8) * 64 + ul * 8;
    GL_LDS(xhi + o, &Ah[seg * 512]);
    GL_LDS(xlo + o, &Al[seg * 512]);
  }
#pragma unroll
  for (int rep = 0; rep < 4; ++rep) {
    const int seg = w + rep * 4;  // 0..15
    size_t o = (size_t)(seg * 8 + lr8) * 64 + ul * 8;
    GL_LDS(wt1h + o, &Bh[seg * 512]);
  }
  if (w < 2) {  // B-lo only for cols 0..15
    size_t o = (size_t)(w * 8 + lr8) * 64 + ul * 8;
    GL_LDS(wt1l + o, &Bl[w * 512]);
  }
  __syncthreads();

  f32x4 acc[2][4];
#pragma unroll
  for (int mf = 0; mf < 2; ++mf)
#pragma unroll
    for (int nf = 0; nf < 4; ++nf) acc[mf][nf] = (f32x4)(0.f);

#pragma unroll
  for (int ks = 0; ks < 2; ++ks) {
    short8 ah[2], bh[4];
#pragma unroll
    for (int mf = 0; mf < 2; ++mf) {
      int row = wr * 32 + mf * 16 + (l & 15);
      int pu = (ks * 4 + (l >> 4)) ^ (row & 7);
      ah[mf] = *(const short8*)&Ah[row * 64 + pu * 8];
    }
#pragma unroll
    for (int nf = 0; nf < 4; ++nf) {
      int col = wc * 64 + nf * 16 + (l & 15);
      int pu = (ks * 4 + (l >> 4)) ^ (col & 7);
      bh[nf] = *(const short8*)&Bh[col * 64 + pu * 8];
    }
#pragma unroll
    for (int mf = 0; mf < 2; ++mf)
#pragma unroll
      for (int nf = 0; nf < 4; ++nf)
        acc[mf][nf] = __builtin_amdgcn_mfma_f32_16x16x32_bf16(ah[mf], bh[nf], acc[mf][nf], 0, 0, 0);
    if (wc == 0) {  // precision correction passes for s-cols fragment
      int col0 = l & 15;
      int puc = (ks * 4 + (l >> 4)) ^ (col0 & 7);
      short8 bl0 = *(const short8*)&Bl[col0 * 64 + puc * 8];
#pragma unroll
      for (int mf = 0; mf < 2; ++mf) {
        int row = wr * 32 + mf * 16 + (l & 15);
        int pu = (ks * 4 + (l >> 4)) ^ (row & 7);
        short8 al = *(const short8*)&Al[row * 64 + pu * 8];
        acc[mf][0] = __builtin_amdgcn_mfma_f32_16x16x32_bf16(ah[mf], bl0, acc[mf][0], 0, 0, 0);
        acc[mf][0] = __builtin_amdgcn_mfma_f32_16x16x32_bf16(al, bh[0], acc[mf][0], 0, 0, 0);
      }
    }
  }
  // epilogue: C/D col=lane&15, row=(lane>>4)*4+reg
#pragma unroll
  for (int mf = 0; mf < 2; ++mf)
#pragma unroll
    for (int nf = 0; nf < 4; ++nf) {
      const int col = wc * 64 + nf * 16 + (l & 15);
      if (col < NSLR) {
        const float bia = bias1[b * 128 + col];
#pragma unroll
        for (int r = 0; r < 4; ++r) {
          int row = rowBase + wr * 32 + mf * 16 + (l >> 4) * 4 + r;
          float vv = acc[mf][nf][r] + bia;
          vv = vv > 0.f ? vv : 0.f;
          if (col < NSn) s_ws[b * 1024 + col * 256 + (row & 255)] = vv;
          else           lr_bf[(size_t)row * NLRn + (col - NSn)] = rneb(vv);
        }
      }
    }
}

// ---- GEMM2: single-pass bf16, K=192, ALL chunks staged upfront, ONE barrier ----
__global__ __launch_bounds__(256) void kgemm2(
    const short* __restrict__ xhi, const short* __restrict__ fm,
    const short* __restrict__ fx, const short* __restrict__ wt2,
    const float* __restrict__ bias2, float* __restrict__ outp) {
  __shared__ __align__(16) short As[3][4096], Bs[3][8192];
  const int t = threadIdx.x, l = t & 63, w = t >> 6;
  const int wr = w >> 1, wc = w & 1;
  const int rowBase = blockIdx.x * 64;
  const int b = rowBase >> 8;
  const int lr8 = l >> 3, ul = (l & 7) ^ lr8;

#pragma unroll
  for (int kc = 0; kc < 3; ++kc) {
    const short* asrc = (kc == 0) ? xhi : (kc == 1) ? fm : fx;
#pragma unroll
    for (int rep = 0; rep < 2; ++rep) {
      const int seg = w + rep * 4;
      size_t o = (size_t)(rowBase + seg * 8 + lr8) * 64 + ul * 8;
      GL_LDS(asrc + o, &As[kc][seg * 512]);
    }
#pragma unroll
    for (int rep = 0; rep < 4; ++rep) {
      const int seg = w + rep * 4;
      size_t o = (size_t)(seg * 8 + lr8) * KB2 + kc * 64 + ul * 8;
      GL_LDS(wt2 + o, &Bs[kc][seg * 512]);
    }
  }
  __syncthreads();

  f32x4 acc[2][4];
#pragma unroll
  for (int mf = 0; mf < 2; ++mf)
#pragma unroll
    for (int nf = 0; nf < 4; ++nf) acc[mf][nf] = (f32x4)(0.f);

#pragma unroll
  for (int kc = 0; kc < 3; ++kc) {
#pragma unroll
    for (int ks = 0; ks < 2; ++ks) {
      short8 a[2], bb[4];
#pragma unroll
      for (int mf = 0; mf < 2; ++mf) {
        int row = wr * 32 + mf * 16 + (l & 15);
        int pu = (ks * 4 + (l >> 4)) ^ (row & 7);
        a[mf] = *(const short8*)&As[kc][row * 64 + pu * 8];
      }
#pragma unroll
      for (int nf = 0; nf < 4; ++nf) {
        int col = wc * 64 + nf * 16 + (l & 15);
        int pu = (ks * 4 + (l >> 4)) ^ (col & 7);
        bb[nf] = *(const short8*)&Bs[kc][col * 64 + pu * 8];
      }
#pragma unroll
      for (int mf = 0; mf < 2; ++mf)
#pragma unroll
        for (int nf = 0; nf < 4; ++nf)
          acc[mf][nf] = __builtin_amdgcn_mfma_f32_16x16x32_bf16(a[mf], bb[nf], acc[mf][nf], 0, 0, 0);
    }
  }
#pragma unroll
  for (int mf = 0; mf < 2; ++mf)
#pragma unroll
    for (int nf = 0; nf < 4; ++nf) {
      const int col = wc * 64 + nf * 16 + (l & 15);
      const float bia = bias2[b * 128 + col];
#pragma unroll
      for (int r = 0; r < 4; ++r) {
        int row = rowBase + wr * 32 + mf * 16 + (l >> 4) * 4 + r;
        float vv = acc[mf][nf][r] + bia;
        outp[(size_t)row * NOUTn + col] = vv > 0.f ? vv : 0.f;
      }
    }
}

// ---- K3: KNN select. 4 rows/wave batched; lr staged in LDS as bf16;
//      gather = half-wave row pairing, 2 features/lane. ----
__device__ __forceinline__ int cntlt(const unsigned* kbr, unsigned c) {
  return __popcll(__ballot(kbr[0] < c)) + __popcll(__ballot(kbr[1] < c)) +
         __popcll(__ballot(kbr[2] < c)) + __popcll(__ballot(kbr[3] < c));
}

__global__ __launch_bounds__(256) void kselect(const float* __restrict__ s_ws,
                                               const unsigned short* __restrict__ lr_bf,
                                               unsigned* __restrict__ fm32,
                                               unsigned* __restrict__ fx32) {
  __shared__ float sT[4][256];
  __shared__ __align__(16) unsigned short lrs[16384];  // [v][64] bf16, 32KB
  __shared__ unsigned int lst[4][4][Kn];
  const int id = blockIdx.x;
  const int xcd = id & 7;
  const int rrx = id >> 3;
  const int b = xcd + 8 * (rrx & 15);   // all 16 seg-blocks of b on one XCD
  const int seg = rrx >> 4;
  const int t = threadIdx.x, lane = t & 63, w = t >> 6;

  {  // stage lr block (32KB) via global_load_lds
    const unsigned short* lrg = lr_bf + (size_t)b * (256 * NLRn);
#pragma unroll
    for (int it = 0; it < 8; ++it)
      GL_LDS(lrg + (it * 256 + t) * 8, &lrs[(it * 256 + t) * 8]);
    const float* sb = s_ws + b * 1024;
    sT[0][t] = sb[t]; sT[1][t] = sb[256 + t];
    sT[2][t] = sb[512 + t]; sT[3][t] = sb[768 + t];
  }
  __syncthreads();

  float sj[4][4];
#pragma unroll
  for (int q = 0; q < 4; ++q)
#pragma unroll
    for (int c = 0; c < 4; ++c) sj[q][c] = sT[c][q * 64 + lane];

  const float C = -14.4269504088896340736f;  // -10 * log2(e)
  unsigned kb[4][4];
  float vv[4][4];
#pragma unroll
  for (int r = 0; r < 4; ++r) {
    const int i = seg * 16 + w * 4 + r;
    const float si0 = sT[0][i], si1 = sT[1][i], si2 = sT[2][i], si3 = sT[3][i];
#pragma unroll
    for (int q = 0; q < 4; ++q) {
      float d0 = sj[q][0] - si0;
      float d1 = sj[q][1] - si1;
      float d2_ = sj[q][2] - si2;
      float d3 = sj[q][3] - si3;
      float dd = ((d0 * d0 + d1 * d1) + d2_ * d2_) + d3 * d3;
      kb[r][q] = __float_as_uint(dd);  // d2 >= 0 -> order-preserving bits
      vv[r][q] = exp2f(C * dd);
    }
  }
  // 4-row-batched exact Kth-smallest bit search
  unsigned T[4] = {0u, 0u, 0u, 0u};
#pragma unroll 1
  for (int bit = 30; bit >= 0; --bit) {
    const unsigned m = 1u << bit;
    unsigned c0 = T[0] | m, c1 = T[1] | m, c2 = T[2] | m, c3 = T[3] | m;
    int n0 = cntlt(kb[0], c0);
    int n1 = cntlt(kb[1], c1);
    int n2 = cntlt(kb[2], c2);
    int n3 = cntlt(kb[3], c3);
    T[0] = (n0 < Kn) ? c0 : T[0];
    T[1] = (n1 < Kn) ? c1 : T[1];
    T[2] = (n2 < Kn) ? c2 : T[2];
    T[3] = (n3 < Kn) ? c3 : T[3];
  }
  // selection scatter (ties ascending-j -> matches stable top_k)
#pragma unroll
  for (int r = 0; r < 4; ++r) {
    const unsigned Tr = T[r];
    int nlt = cntlt(kb[r], Tr);
    int rem = Kn - nlt;
    int base = 0, ecum = 0;
#pragma unroll
    for (int q = 0; q < 4; ++q) {
      bool lt = kb[r][q] < Tr;
      bool eq = kb[r][q] == Tr;
      unsigned long long meq = __ballot(eq);
      int eqrank = ecum + mbcnt64(meq);
      bool sel = lt || (eq && (eqrank < rem));
      unsigned long long msel = __ballot(sel);
      int pos = base + mbcnt64(msel);
      if (sel)
        lst[w][r][pos] = (__float_as_uint(vv[r][q]) & 0xFFFFFF00u) | (unsigned)(q * 64 + lane);
      base += __popcll(msel);
      ecum += __popcll(meq);
    }
  }
  // gather: half-wave = row, lane&31 = feature pair, lr from LDS bf16x2
  const int h = lane >> 5;   // 0: row 2p, 1: row 2p+1
  const int f2 = lane & 31;  // feature pair index
#pragma unroll
  for (int p = 0; p < 2; ++p) {
    const unsigned* lstp = &lst[w][2 * p + h][0];
    float am0 = 0.f, am1 = 0.f, ax0 = 0.f, ax1 = 0.f;
#pragma unroll 4
    for (int tt = 0; tt < Kn; ++tt) {
      unsigned pk = lstp[tt];
      float v = __uint_as_float(pk & 0xFFFFFF00u);
      unsigned off = (pk & 0xFFu) << 6;  // j*64 u16 elems
      unsigned pr = *(const unsigned*)&lrs[off + f2 * 2];
      float l0 = __uint_as_float(pr << 16);
      float l1 = __uint_as_float(pr & 0xFFFF0000u);
      float t0 = v * l0, t1 = v * l1;
      am0 += t0; am1 += t1;
      ax0 = fmaxf(ax0, t0); ax1 = fmaxf(ax1, t1);
    }
    const int i = seg * 16 + w * 4 + 2 * p + h;
    size_t ro = ((size_t)(b * 256 + i)) * 32 + f2;  // u32 units
    am0 *= (1.f / 40.f); am1 *= (1.f / 40.f);
    fm32[ro] = (unsigned)rneb(am0) | ((unsigned)rneb(am1) << 16);
    fx32[ro] = (unsigned)rneb(ax0) | ((unsigned)rneb(ax1) << 16);
  }
}

extern "C" void kernel_launch(void* const* d_in, const int* in_sizes, int n_in,
                              void* d_out, int out_size, void* d_ws, size_t ws_size,
                              hipStream_t stream) {
  const float* x = (const float*)d_in[0];
  const float* W_slr = (const float*)d_in[1];
  const float* b_slr = (const float*)d_in[2];
  const float* W_out = (const float*)d_in[3];
  const float* b_out = (const float*)d_in[4];
  float* out = (float*)d_out;

  char* p = (char*)d_ws;
  auto take = [&](size_t bytes) { char* c = p; p += (bytes + 255) & ~(size_t)255; return c; };
  short* xhi = (short*)take((size_t)ROWS * 64 * 2);
  short* xlo = (short*)take((size_t)ROWS * 64 * 2);
  short* wt1h = (short*)take(128 * 64 * 2);
  short* wt1l = (short*)take(128 * 64 * 2);
  short* wt2 = (short*)take(128 * KB2 * 2);
  float* bias1 = (float*)take(Bn * 128 * 4);
  float* bias2 = (float*)take(Bn * 128 * 4);
  float* s_ws = (float*)take(Bn * 1024 * 4);
  unsigned short* lr_bf = (unsigned short*)take((size_t)ROWS * 64 * 2);
  short* fm = (short*)take((size_t)ROWS * 64 * 2);
  short* fx = (short*)take((size_t)ROWS * 64 * 2);

  kprep<<<256, 256, 0, stream>>>(x, W_slr, b_slr, W_out, b_out,
                                 xhi, xlo, wt1h, wt1l, wt2, bias1, bias2);
  kgemm1<<<ROWS / 64, 256, 0, stream>>>(xhi, xlo, wt1h, wt1l, bias1, s_ws, lr_bf);
  kselect<<<Bn * 16, 256, 0, stream>>>(s_ws, lr_bf, (unsigned*)fm, (unsigned*)fx);
  kgemm2<<<ROWS / 64, 256, 0, stream>>>(xhi, fm, fx, wt2, bias2, out);
}

// Round 10
// 131.302 us; speedup vs baseline: 1.0126x; 1.0126x over previous
//
#include <hip/hip_runtime.h>

constexpr int Bn = 128, Vn = 256, Fn = 64;
constexpr int NSLR = 68, NSn = 4, NLRn = 64;
constexpr int Kn = 40, NOUTn = 128;
constexpr int ROWS = Bn * Vn;  // 32768
constexpr int KB2 = 192;       // GEMM2 K (x 64 | ftm 64 | ftx 64)

typedef __attribute__((ext_vector_type(8))) short short8;
typedef __attribute__((ext_vector_type(4))) float f32x4;

__device__ __forceinline__ int mbcnt64(unsigned long long m) {
  return __builtin_amdgcn_mbcnt_hi((unsigned)(m >> 32),
         __builtin_amdgcn_mbcnt_lo((unsigned)(m & 0xFFFFFFFFull), 0));
}
__device__ __forceinline__ unsigned short rneb(float v) {  // fp32 -> bf16 RNE
  unsigned u = __float_as_uint(v);
  unsigned r = u + 0x7FFFu + ((u >> 16) & 1u);
  return (unsigned short)(r >> 16);
}
__device__ __forceinline__ float bf2f(unsigned short h) {
  return __uint_as_float(((unsigned)h) << 16);
}
#define GL_LDS(gp, lp) __builtin_amdgcn_global_load_lds( \
    (const __attribute__((address_space(1))) void*)(gp), \
    (__attribute__((address_space(3))) void*)(lp), 16, 0, 0)

// ---- K0: all prep. blocks 0..127: x split + xmean + bias1/bias2 (per b).
//          blocks 128..255: W transpose/split. ----
__global__ __launch_bounds__(256) void kprep(
    const float* __restrict__ x,
    const float* __restrict__ W_slr, const float* __restrict__ b_slr,
    const float* __restrict__ W_out, const float* __restrict__ b_out,
    short* __restrict__ xhi, short* __restrict__ xlo,
    short* __restrict__ wt1h, short* __restrict__ wt1l, short* __restrict__ wt2,
    float* __restrict__ bias1, float* __restrict__ bias2) {
  const int blk = blockIdx.x, t = threadIdx.x;
  if (blk >= Bn) {  // ---- W prep ----
    const int col = blk - Bn;  // 0..127
    if (t < 64) {
      float val = (col < NSLR) ? W_slr[t * NSLR + col] : 0.f;
      unsigned short h = rneb(val);
      wt1h[col * 64 + t] = (short)h;
      wt1l[col * 64 + t] = (short)rneb(val - bf2f(h));
    } else {
      int k = t - 64;                   // 0..191
      int row = (k < 64) ? k : 64 + k;  // skip xmean rows 64..127
      wt2[col * KB2 + k] = (short)rneb(W_out[row * NOUTn + col]);
    }
    return;
  }
  // ---- x prep for b = blk ----
  const int b = blk;
  const int f4 = t & 15, vg = t >> 4;
  const float4* xb = (const float4*)(x + (size_t)b * 16384);
  float4 sum = make_float4(0.f, 0.f, 0.f, 0.f);
  for (int i = 0; i < 16; ++i) {
    int v = vg * 16 + i;
    float4 val = xb[v * 16 + f4];
    sum.x += val.x; sum.y += val.y; sum.z += val.z; sum.w += val.w;
    unsigned short h0 = rneb(val.x), h1 = rneb(val.y), h2 = rneb(val.z), h3 = rneb(val.w);
    short4 hi = {(short)h0, (short)h1, (short)h2, (short)h3};
    short4 lo = {(short)rneb(val.x - bf2f(h0)), (short)rneb(val.y - bf2f(h1)),
                 (short)rneb(val.z - bf2f(h2)), (short)rneb(val.w - bf2f(h3))};
    size_t o = (size_t)b * 4096 + v * 16 + f4;
    ((short4*)xhi)[o] = hi;
    ((short4*)xlo)[o] = lo;
  }
  __shared__ float4 ps[16][16];
  __shared__ float xms[64];
  ps[vg][f4] = sum;
  __syncthreads();
  if (t < 16) {
    float4 m = ps[0][t];
    for (int g = 1; g < 16; ++g) {
      float4 v = ps[g][t];
      m.x += v.x; m.y += v.y; m.z += v.z; m.w += v.w;
    }
    m.x *= (1.f / 256.f); m.y *= (1.f / 256.f); m.z *= (1.f / 256.f); m.w *= (1.f / 256.f);
    ((float4*)xms)[t] = m;
  }
  __syncthreads();
  if (t < 128) {
    float acc = b_out[t];
    for (int f = 0; f < 64; ++f) acc = fmaf(xms[f], W_out[(64 + f) * NOUTn + t], acc);
    bias2[b * 128 + t] = acc;
  } else {
    int c = t - 128;
    if (c < NSLR) {
      float acc = b_slr[c];
      for (int f = 0; f < 64; ++f) acc = fmaf(xms[f], W_slr[(64 + f) * NSLR + c], acc);
      bias1[b * 128 + c] = acc;
    }
  }
}

// ---- GEMM1: K=64, tile 64x128, 4 waves. 3-pass hi/lo for the s-fragment only;
//      lr single-pass bf16, emitted as bf16 u16. ----
__global__ __launch_bounds__(256) void kgemm1(
    const short* __restrict__ xhi, const short* __restrict__ xlo,
    const short* __restrict__ wt1h, const short* __restrict__ wt1l,
    const float* __restrict__ bias1,
    float* __restrict__ s_ws, unsigned short* __restrict__ lr_bf) {
  __shared__ __align__(16) short Ah[4096], Al[4096], Bh[8192], Bl[1024];
  const int t = threadIdx.x, l = t & 63, w = t >> 6;
  const int wr = w >> 1, wc = w & 1;
  const int rowBase = blockIdx.x * 64;
  const int b = rowBase >> 8;
  const int lr8 = l >> 3, ul = (l & 7) ^ lr8;

#pragma unroll
  for (int rep = 0; rep < 2; ++rep) {
    const int seg = w + rep * 4;  // 0..7
    size_t o = (size_t)(rowBase + seg * 8 + lr8) * 64 + ul * 8;
    GL_LDS(xhi + o, &Ah[seg * 512]);
    GL_LDS(xlo + o, &Al[seg * 512]);
  }
#pragma unroll
  for (int rep = 0; rep < 4; ++rep) {
    const int seg = w + rep * 4;  // 0..15
    size_t o = (size_t)(seg * 8 + lr8) * 64 + ul * 8;
    GL_LDS(wt1h + o, &Bh[seg * 512]);
  }
  if (w < 2) {  // B-lo only for cols 0..15
    size_t o = (size_t)(w * 8 + lr8) * 64 + ul * 8;
    GL_LDS(wt1l + o, &Bl[w * 512]);
  }
  __syncthreads();

  f32x4 acc[2][4];
#pragma unroll
  for (int mf = 0; mf < 2; ++mf)
#pragma unroll
    for (int nf = 0; nf < 4; ++nf) acc[mf][nf] = (f32x4)(0.f);

#pragma unroll
  for (int ks = 0; ks < 2; ++ks) {
    short8 ah[2], bh[4];
#pragma unroll
    for (int mf = 0; mf < 2; ++mf) {
      int row = wr * 32 + mf * 16 + (l & 15);
      int pu = (ks * 4 + (l >> 4)) ^ (row & 7);
      ah[mf] = *(const short8*)&Ah[row * 64 + pu * 8];
    }
#pragma unroll
    for (int nf = 0; nf < 4; ++nf) {
      int col = wc * 64 + nf * 16 + (l & 15);
      int pu = (ks * 4 + (l >> 4)) ^ (col & 7);
      bh[nf] = *(const short8*)&Bh[col * 64 + pu * 8];
    }
#pragma unroll
    for (int mf = 0; mf < 2; ++mf)
#pragma unroll
      for (int nf = 0; nf < 4; ++nf)
        acc[mf][nf] = __builtin_amdgcn_mfma_f32_16x16x32_bf16(ah[mf], bh[nf], acc[mf][nf], 0, 0, 0);
    if (wc == 0) {  // precision correction passes for s-cols fragment
      int col0 = l & 15;
      int puc = (ks * 4 + (l >> 4)) ^ (col0 & 7);
      short8 bl0 = *(const short8*)&Bl[col0 * 64 + puc * 8];
#pragma unroll
      for (int mf = 0; mf < 2; ++mf) {
        int row = wr * 32 + mf * 16 + (l & 15);
        int pu = (ks * 4 + (l >> 4)) ^ (row & 7);
        short8 al = *(const short8*)&Al[row * 64 + pu * 8];
        acc[mf][0] = __builtin_amdgcn_mfma_f32_16x16x32_bf16(ah[mf], bl0, acc[mf][0], 0, 0, 0);
        acc[mf][0] = __builtin_amdgcn_mfma_f32_16x16x32_bf16(al, bh[0], acc[mf][0], 0, 0, 0);
      }
    }
  }
  // epilogue: C/D col=lane&15, row=(lane>>4)*4+reg
#pragma unroll
  for (int mf = 0; mf < 2; ++mf)
#pragma unroll
    for (int nf = 0; nf < 4; ++nf) {
      const int col = wc * 64 + nf * 16 + (l & 15);
      if (col < NSLR) {
        const float bia = bias1[b * 128 + col];
#pragma unroll
        for (int r = 0; r < 4; ++r) {
          int row = rowBase + wr * 32 + mf * 16 + (l >> 4) * 4 + r;
          float vv = acc[mf][nf][r] + bia;
          vv = vv > 0.f ? vv : 0.f;
          if (col < NSn) s_ws[b * 1024 + col * 256 + (row & 255)] = vv;
          else           lr_bf[(size_t)row * NLRn + (col - NSn)] = rneb(vv);
        }
      }
    }
}

// ---- GEMM2: single-pass bf16, K=192, ALL chunks staged upfront, ONE barrier ----
__global__ __launch_bounds__(256) void kgemm2(
    const short* __restrict__ xhi, const short* __restrict__ fm,
    const short* __restrict__ fx, const short* __restrict__ wt2,
    const float* __restrict__ bias2, float* __restrict__ outp) {
  __shared__ __align__(16) short As[3][4096], Bs[3][8192];
  const int t = threadIdx.x, l = t & 63, w = t >> 6;
  const int wr = w >> 1, wc = w & 1;
  const int rowBase = blockIdx.x * 64;
  const int b = rowBase >> 8;
  const int lr8 = l >> 3, ul = (l & 7) ^ lr8;

#pragma unroll
  for (int kc = 0; kc < 3; ++kc) {
    const short* asrc = (kc == 0) ? xhi : (kc == 1) ? fm : fx;
#pragma unroll
    for (int rep = 0; rep < 2; ++rep) {
      const int seg = w + rep * 4;
      size_t o = (size_t)(rowBase + seg * 8 + lr8) * 64 + ul * 8;
      GL_LDS(asrc + o, &As[kc][seg * 512]);
    }
#pragma unroll
    for (int rep = 0; rep < 4; ++rep) {
      const int seg = w + rep * 4;
      size_t o = (size_t)(seg * 8 + lr8) * KB2 + kc * 64 + ul * 8;
      GL_LDS(wt2 + o, &Bs[kc][seg * 512]);
    }
  }
  __syncthreads();

  f32x4 acc[2][4];
#pragma unroll
  for (int mf = 0; mf < 2; ++mf)
#pragma unroll
    for (int nf = 0; nf < 4; ++nf) acc[mf][nf] = (f32x4)(0.f);

#pragma unroll
  for (int kc = 0; kc < 3; ++kc) {
#pragma unroll
    for (int ks = 0; ks < 2; ++ks) {
      short8 a[2], bb[4];
#pragma unroll
      for (int mf = 0; mf < 2; ++mf) {
        int row = wr * 32 + mf * 16 + (l & 15);
        int pu = (ks * 4 + (l >> 4)) ^ (row & 7);
        a[mf] = *(const short8*)&As[kc][row * 64 + pu * 8];
      }
#pragma unroll
      for (int nf = 0; nf < 4; ++nf) {
        int col = wc * 64 + nf * 16 + (l & 15);
        int pu = (ks * 4 + (l >> 4)) ^ (col & 7);
        bb[nf] = *(const short8*)&Bs[kc][col * 64 + pu * 8];
      }
#pragma unroll
      for (int mf = 0; mf < 2; ++mf)
#pragma unroll
        for (int nf = 0; nf < 4; ++nf)
          acc[mf][nf] = __builtin_amdgcn_mfma_f32_16x16x32_bf16(a[mf], bb[nf], acc[mf][nf], 0, 0, 0);
    }
  }
#pragma unroll
  for (int mf = 0; mf < 2; ++mf)
#pragma unroll
    for (int nf = 0; nf < 4; ++nf) {
      const int col = wc * 64 + nf * 16 + (l & 15);
      const float bia = bias2[b * 128 + col];
#pragma unroll
      for (int r = 0; r < 4; ++r) {
        int row = rowBase + wr * 32 + mf * 16 + (l >> 4) * 4 + r;
        float vv = acc[mf][nf][r] + bia;
        outp[(size_t)row * NOUTn + col] = vv > 0.f ? vv : 0.f;
      }
    }
}

// ---- K3: KNN select. 8 rows/wave batched; per-lane LDS lst reads (NO
//      readfirstlane: lst row differs per half-wave) ----
__device__ __forceinline__ int cntlt(const unsigned* kbr, unsigned c) {
  return __popcll(__ballot(kbr[0] < c)) + __popcll(__ballot(kbr[1] < c)) +
         __popcll(__ballot(kbr[2] < c)) + __popcll(__ballot(kbr[3] < c));
}

__global__ __launch_bounds__(256) void kselect(const float* __restrict__ s_ws,
                                               const unsigned short* __restrict__ lr_bf,
                                               unsigned* __restrict__ fm32,
                                               unsigned* __restrict__ fx32) {
  __shared__ float sT[4][256];
  __shared__ unsigned int lst[4][8][Kn];
  const int id = blockIdx.x;                 // 1024 blocks
  const int xcd = id & 7;
  const int k_ = id >> 3;                    // 0..127
  const int b = xcd + 8 * (k_ & 15);         // all 8 seg-blocks of b on one XCD
  const int seg = k_ >> 4;                   // 0..7 (32 rows each)
  const int t = threadIdx.x, lane = t & 63, w = t >> 6;

  {
    const float* sb = s_ws + b * 1024;
    sT[0][t] = sb[t]; sT[1][t] = sb[256 + t];
    sT[2][t] = sb[512 + t]; sT[3][t] = sb[768 + t];
  }
  __syncthreads();

  float sj[4][4];
#pragma unroll
  for (int q = 0; q < 4; ++q)
#pragma unroll
    for (int c = 0; c < 4; ++c) sj[q][c] = sT[c][q * 64 + lane];

  const float C = -14.4269504088896340736f;  // -10 * log2(e)
  unsigned kb[8][4];
#pragma unroll
  for (int r = 0; r < 8; ++r) {
    const int i = seg * 32 + w * 8 + r;
    const float si0 = sT[0][i], si1 = sT[1][i], si2 = sT[2][i], si3 = sT[3][i];
#pragma unroll
    for (int q = 0; q < 4; ++q) {
      float d0 = sj[q][0] - si0;
      float d1 = sj[q][1] - si1;
      float d2_ = sj[q][2] - si2;
      float d3 = sj[q][3] - si3;
      float dd = ((d0 * d0 + d1 * d1) + d2_ * d2_) + d3 * d3;
      kb[r][q] = __float_as_uint(dd);  // d2 >= 0 -> order-preserving bits
    }
  }
  // 8-row-batched exact Kth-smallest bit search (32 indep cmp per round)
  unsigned T[8] = {0u, 0u, 0u, 0u, 0u, 0u, 0u, 0u};
#pragma unroll 1
  for (int bit = 30; bit >= 0; --bit) {
    const unsigned m = 1u << bit;
    unsigned cnd[8];
    int n[8];
#pragma unroll
    for (int r = 0; r < 8; ++r) cnd[r] = T[r] | m;
#pragma unroll
    for (int r = 0; r < 8; ++r) n[r] = cntlt(kb[r], cnd[r]);
#pragma unroll
    for (int r = 0; r < 8; ++r) T[r] = (n[r] < Kn) ? cnd[r] : T[r];
  }
  // selection scatter (ties ascending-j -> matches stable top_k); v recomputed
#pragma unroll
  for (int r = 0; r < 8; ++r) {
    const unsigned Tr = T[r];
    int nlt = cntlt(kb[r], Tr);
    int rem = Kn - nlt;
    int base = 0, ecum = 0;
#pragma unroll
    for (int q = 0; q < 4; ++q) {
      bool lt = kb[r][q] < Tr;
      bool eq = kb[r][q] == Tr;
      unsigned long long meq = __ballot(eq);
      int eqrank = ecum + mbcnt64(meq);
      bool sel = lt || (eq && (eqrank < rem));
      unsigned long long msel = __ballot(sel);
      int pos = base + mbcnt64(msel);
      float v = exp2f(C * __uint_as_float(kb[r][q]));
      if (sel)
        lst[w][r][pos] = (__float_as_uint(v) & 0xFFFFFF00u) | (unsigned)(q * 64 + lane);
      base += __popcll(msel);
      ecum += __popcll(meq);
    }
  }
  // gather: half-wave = row-in-pair, lane&31 = feature pair; per-lane LDS lst
  const int h = lane >> 5;
  const int f2 = lane & 31;
  const unsigned short* lrb = lr_bf + (size_t)b * (256 * NLRn);
#pragma unroll
  for (int p = 0; p < 4; ++p) {
    const unsigned* lstp = &lst[w][2 * p + h][0];
    float am0 = 0.f, am1 = 0.f, ax0 = 0.f, ax1 = 0.f;
#pragma unroll 4
    for (int tt = 0; tt < Kn; ++tt) {
      unsigned pk = lstp[tt];  // same addr within half-wave -> LDS broadcast
      float v = __uint_as_float(pk & 0xFFFFFF00u);
      unsigned pr = *(const unsigned*)(lrb + ((pk & 0xFFu) << 6) + f2 * 2);
      float l0 = __uint_as_float(pr << 16);
      float l1 = __uint_as_float(pr & 0xFFFF0000u);
      float t0 = v * l0, t1 = v * l1;
      am0 += t0; am1 += t1;
      ax0 = fmaxf(ax0, t0); ax1 = fmaxf(ax1, t1);
    }
    const int i = seg * 32 + w * 8 + 2 * p + h;
    size_t ro = ((size_t)(b * 256 + i)) * 32 + f2;  // u32 units
    am0 *= (1.f / 40.f); am1 *= (1.f / 40.f);
    fm32[ro] = (unsigned)rneb(am0) | ((unsigned)rneb(am1) << 16);
    fx32[ro] = (unsigned)rneb(ax0) | ((unsigned)rneb(ax1) << 16);
  }
}

extern "C" void kernel_launch(void* const* d_in, const int* in_sizes, int n_in,
                              void* d_out, int out_size, void* d_ws, size_t ws_size,
                              hipStream_t stream) {
  const float* x = (const float*)d_in[0];
  const float* W_slr = (const float*)d_in[1];
  const float* b_slr = (const float*)d_in[2];
  const float* W_out = (const float*)d_in[3];
  const float* b_out = (const float*)d_in[4];
  float* out = (float*)d_out;

  char* p = (char*)d_ws;
  auto take = [&](size_t bytes) { char* c = p; p += (bytes + 255) & ~(size_t)255; return c; };
  short* xhi = (short*)take((size_t)ROWS * 64 * 2);
  short* xlo = (short*)take((size_t)ROWS * 64 * 2);
  short* wt1h = (short*)take(128 * 64 * 2);
  short* wt1l = (short*)take(128 * 64 * 2);
  short* wt2 = (short*)take(128 * KB2 * 2);
  float* bias1 = (float*)take(Bn * 128 * 4);
  float* bias2 = (float*)take(Bn * 128 * 4);
  float* s_ws = (float*)take(Bn * 1024 * 4);
  unsigned short* lr_bf = (unsigned short*)take((size_t)ROWS * 64 * 2);
  short* fm = (short*)take((size_t)ROWS * 64 * 2);
  short* fx = (short*)take((size_t)ROWS * 64 * 2);

  kprep<<<256, 256, 0, stream>>>(x, W_slr, b_slr, W_out, b_out,
                                 xhi, xlo, wt1h, wt1l, wt2, bias1, bias2);
  kgemm1<<<ROWS / 64, 256, 0, stream>>>(xhi, xlo, wt1h, wt1l, bias1, s_ws, lr_bf);
  kselect<<<Bn * 8, 256, 0, stream>>>(s_ws, lr_bf, (unsigned*)fm, (unsigned*)fx);
  kgemm2<<<ROWS / 64, 256, 0, stream>>>(xhi, fm, fx, wt2, bias2, out);
}

// Round 11
// 122.394 us; speedup vs baseline: 1.0863x; 1.0728x over previous
//
#include <hip/hip_runtime.h>

constexpr int Bn = 128, Vn = 256, Fn = 64;
constexpr int NSLR = 68, NSn = 4, NLRn = 64;
constexpr int Kn = 40, NOUTn = 128;
constexpr int ROWS = Bn * Vn;  // 32768
constexpr int KB2 = 192;       // GEMM2 K (x 64 | ftm 64 | ftx 64)

typedef __attribute__((ext_vector_type(8))) short short8;
typedef __attribute__((ext_vector_type(4))) float f32x4;

__device__ __forceinline__ int mbcnt64(unsigned long long m) {
  return __builtin_amdgcn_mbcnt_hi((unsigned)(m >> 32),
         __builtin_amdgcn_mbcnt_lo((unsigned)(m & 0xFFFFFFFFull), 0));
}
__device__ __forceinline__ unsigned short rneb(float v) {  // fp32 -> bf16 RNE
  unsigned u = __float_as_uint(v);
  unsigned r = u + 0x7FFFu + ((u >> 16) & 1u);
  return (unsigned short)(r >> 16);
}
#define GL_LDS(gp, lp) __builtin_amdgcn_global_load_lds( \
    (const __attribute__((address_space(1))) void*)(gp), \
    (__attribute__((address_space(3))) void*)(lp), 16, 0, 0)

// ---- K0: blocks 0..127 (per b): stage x in LDS, xhi bf16, xmean,
//      bias1lr/bias2 fold, and s = EXACT fp32 4-col GEMV per row.
//      blocks 128..255: W transpose/convert. ----
__global__ __launch_bounds__(256) void kprep(
    const float* __restrict__ x,
    const float* __restrict__ W_slr, const float* __restrict__ b_slr,
    const float* __restrict__ W_out, const float* __restrict__ b_out,
    short* __restrict__ xhi, short* __restrict__ wt1, short* __restrict__ wt2,
    float* __restrict__ bias1lr, float* __restrict__ bias2,
    float* __restrict__ s_ws) {
  const int blk = blockIdx.x, t = threadIdx.x;
  __shared__ float xs[256 * 65];   // x rows, stride 65 (conflict-free col reads)
  __shared__ float4 ps[16][16];
  __shared__ float xms[64];
  __shared__ float wss[256];       // W_slr[k<64][c<4]
  __shared__ float bS[4];
  if (blk >= Bn) {  // ---- W prep ----
    const int col = blk - Bn;  // 0..127
    if (t < 64) {
      if (col < 64) wt1[col * 64 + t] = (short)rneb(W_slr[t * NSLR + 4 + col]);
    } else {
      int k = t - 64;                   // 0..191
      int row = (k < 64) ? k : 64 + k;  // skip xmean rows 64..127
      wt2[col * KB2 + k] = (short)rneb(W_out[row * NOUTn + col]);
    }
    return;
  }
  // ---- x prep for b = blk ----
  const int b = blk;
  wss[t] = W_slr[(t >> 2) * NSLR + (t & 3)];
  const int f4 = t & 15, vg = t >> 4;
  const float4* xb = (const float4*)(x + (size_t)b * 16384);
  float4 sum = make_float4(0.f, 0.f, 0.f, 0.f);
  for (int i = 0; i < 16; ++i) {
    int v = vg * 16 + i;
    float4 val = xb[v * 16 + f4];
    sum.x += val.x; sum.y += val.y; sum.z += val.z; sum.w += val.w;
    short4 hi = {(short)rneb(val.x), (short)rneb(val.y),
                 (short)rneb(val.z), (short)rneb(val.w)};
    ((short4*)xhi)[(size_t)b * 4096 + v * 16 + f4] = hi;
    float* xr = &xs[v * 65 + f4 * 4];
    xr[0] = val.x; xr[1] = val.y; xr[2] = val.z; xr[3] = val.w;
  }
  ps[vg][f4] = sum;
  __syncthreads();
  if (t < 16) {
    float4 m = ps[0][t];
    for (int g = 1; g < 16; ++g) {
      float4 v = ps[g][t];
      m.x += v.x; m.y += v.y; m.z += v.z; m.w += v.w;
    }
    m.x *= (1.f / 256.f); m.y *= (1.f / 256.f); m.z *= (1.f / 256.f); m.w *= (1.f / 256.f);
    ((float4*)xms)[t] = m;
  }
  __syncthreads();
  // fold xmean into biases (fp32 exact)
  if (t < 128) {
    float acc = b_out[t];
    for (int f = 0; f < 64; ++f) acc = fmaf(xms[f], W_out[(64 + f) * NOUTn + t], acc);
    bias2[b * 128 + t] = acc;
  } else if (t < 192) {
    int c = t - 128;
    float acc = b_slr[4 + c];
    for (int f = 0; f < 64; ++f) acc = fmaf(xms[f], W_slr[(64 + f) * NSLR + 4 + c], acc);
    bias1lr[b * 64 + c] = acc;
  } else if (t < 196) {
    int c = t - 192;
    float acc = b_slr[c];
    for (int f = 0; f < 64; ++f) acc = fmaf(xms[f], W_slr[(64 + f) * NSLR + c], acc);
    bS[c] = acc;
  }
  __syncthreads();
  // s for row t (exact fp32): dot(x_row, W[:,c]) + bS[c], relu
  float a0 = bS[0], a1 = bS[1], a2 = bS[2], a3 = bS[3];
  for (int k = 0; k < 64; ++k) {
    float xv = xs[t * 65 + k];              // bank (t+k)%32: conflict-free
    a0 = fmaf(xv, wss[k * 4 + 0], a0);      // wss uniform -> broadcast
    a1 = fmaf(xv, wss[k * 4 + 1], a1);
    a2 = fmaf(xv, wss[k * 4 + 2], a2);
    a3 = fmaf(xv, wss[k * 4 + 3], a3);
  }
  s_ws[b * 1024 + 0 * 256 + t] = fmaxf(a0, 0.f);
  s_ws[b * 1024 + 1 * 256 + t] = fmaxf(a1, 0.f);
  s_ws[b * 1024 + 2 * 256 + t] = fmaxf(a2, 0.f);
  s_ws[b * 1024 + 3 * 256 + t] = fmaxf(a3, 0.f);
}

// ---- GEMM1 (lr only): single-pass bf16, tile 64x64, K=64, 4 waves ----
__global__ __launch_bounds__(256) void kgemm1(
    const short* __restrict__ xhi, const short* __restrict__ wt1,
    const float* __restrict__ bias1lr, unsigned short* __restrict__ lr_bf) {
  __shared__ __align__(16) short As[4096], Bs[4096];
  const int t = threadIdx.x, l = t & 63, w = t >> 6;
  const int wr = w >> 1, wc = w & 1;
  const int rowBase = blockIdx.x * 64;
  const int b = rowBase >> 8;
  const int lr8 = l >> 3, ul = (l & 7) ^ lr8;

#pragma unroll
  for (int rep = 0; rep < 2; ++rep) {
    const int seg = w + rep * 4;  // 0..7
    GL_LDS(xhi + (size_t)(rowBase + seg * 8 + lr8) * 64 + ul * 8, &As[seg * 512]);
    GL_LDS(wt1 + (size_t)(seg * 8 + lr8) * 64 + ul * 8, &Bs[seg * 512]);
  }
  __syncthreads();

  f32x4 acc[2][2];
#pragma unroll
  for (int mf = 0; mf < 2; ++mf)
#pragma unroll
    for (int nf = 0; nf < 2; ++nf) acc[mf][nf] = (f32x4)(0.f);

#pragma unroll
  for (int ks = 0; ks < 2; ++ks) {
    short8 a[2], bb[2];
#pragma unroll
    for (int mf = 0; mf < 2; ++mf) {
      int row = wr * 32 + mf * 16 + (l & 15);
      int pu = (ks * 4 + (l >> 4)) ^ (row & 7);
      a[mf] = *(const short8*)&As[row * 64 + pu * 8];
    }
#pragma unroll
    for (int nf = 0; nf < 2; ++nf) {
      int col = wc * 32 + nf * 16 + (l & 15);
      int pu = (ks * 4 + (l >> 4)) ^ (col & 7);
      bb[nf] = *(const short8*)&Bs[col * 64 + pu * 8];
    }
#pragma unroll
    for (int mf = 0; mf < 2; ++mf)
#pragma unroll
      for (int nf = 0; nf < 2; ++nf)
        acc[mf][nf] = __builtin_amdgcn_mfma_f32_16x16x32_bf16(a[mf], bb[nf], acc[mf][nf], 0, 0, 0);
  }
  // epilogue: C/D col=lane&15, row=(lane>>4)*4+reg
#pragma unroll
  for (int mf = 0; mf < 2; ++mf)
#pragma unroll
    for (int nf = 0; nf < 2; ++nf) {
      const int col = wc * 32 + nf * 16 + (l & 15);
      const float bia = bias1lr[b * 64 + col];
#pragma unroll
      for (int r = 0; r < 4; ++r) {
        int row = rowBase + wr * 32 + mf * 16 + (l >> 4) * 4 + r;
        float vv = acc[mf][nf][r] + bia;
        lr_bf[(size_t)row * NLRn + col] = rneb(vv > 0.f ? vv : 0.f);
      }
    }
}

// ---- GEMM2: single-pass bf16, K=192, ALL chunks staged upfront, ONE barrier ----
__global__ __launch_bounds__(256) void kgemm2(
    const short* __restrict__ xhi, const short* __restrict__ fm,
    const short* __restrict__ fx, const short* __restrict__ wt2,
    const float* __restrict__ bias2, float* __restrict__ outp) {
  __shared__ __align__(16) short As[3][4096], Bs[3][8192];
  const int t = threadIdx.x, l = t & 63, w = t >> 6;
  const int wr = w >> 1, wc = w & 1;
  const int rowBase = blockIdx.x * 64;
  const int b = rowBase >> 8;
  const int lr8 = l >> 3, ul = (l & 7) ^ lr8;

#pragma unroll
  for (int kc = 0; kc < 3; ++kc) {
    const short* asrc = (kc == 0) ? xhi : (kc == 1) ? fm : fx;
#pragma unroll
    for (int rep = 0; rep < 2; ++rep) {
      const int seg = w + rep * 4;
      GL_LDS(asrc + (size_t)(rowBase + seg * 8 + lr8) * 64 + ul * 8, &As[kc][seg * 512]);
    }
#pragma unroll
    for (int rep = 0; rep < 4; ++rep) {
      const int seg = w + rep * 4;
      GL_LDS(wt2 + (size_t)(seg * 8 + lr8) * KB2 + kc * 64 + ul * 8, &Bs[kc][seg * 512]);
    }
  }
  __syncthreads();

  f32x4 acc[2][4];
#pragma unroll
  for (int mf = 0; mf < 2; ++mf)
#pragma unroll
    for (int nf = 0; nf < 4; ++nf) acc[mf][nf] = (f32x4)(0.f);

#pragma unroll
  for (int kc = 0; kc < 3; ++kc) {
#pragma unroll
    for (int ks = 0; ks < 2; ++ks) {
      short8 a[2], bb[4];
#pragma unroll
      for (int mf = 0; mf < 2; ++mf) {
        int row = wr * 32 + mf * 16 + (l & 15);
        int pu = (ks * 4 + (l >> 4)) ^ (row & 7);
        a[mf] = *(const short8*)&As[kc][row * 64 + pu * 8];
      }
#pragma unroll
      for (int nf = 0; nf < 4; ++nf) {
        int col = wc * 64 + nf * 16 + (l & 15);
        int pu = (ks * 4 + (l >> 4)) ^ (col & 7);
        bb[nf] = *(const short8*)&Bs[kc][col * 64 + pu * 8];
      }
#pragma unroll
      for (int mf = 0; mf < 2; ++mf)
#pragma unroll
        for (int nf = 0; nf < 4; ++nf)
          acc[mf][nf] = __builtin_amdgcn_mfma_f32_16x16x32_bf16(a[mf], bb[nf], acc[mf][nf], 0, 0, 0);
    }
  }
#pragma unroll
  for (int mf = 0; mf < 2; ++mf)
#pragma unroll
    for (int nf = 0; nf < 4; ++nf) {
      const int col = wc * 64 + nf * 16 + (l & 15);
      const float bia = bias2[b * 128 + col];
#pragma unroll
      for (int r = 0; r < 4; ++r) {
        int row = rowBase + wr * 32 + mf * 16 + (l >> 4) * 4 + r;
        float vv = acc[mf][nf][r] + bia;
        outp[(size_t)row * NOUTn + col] = vv > 0.f ? vv : 0.f;
      }
    }
}

// ---- K3: KNN select. Round-6 geometry (grid 2048, 4 rows/wave, 16 rows/blk);
//      bf16 lr gathers, v recomputed in scatter, merged pair gather loops. ----
__device__ __forceinline__ int cntlt(const unsigned* kbr, unsigned c) {
  return __popcll(__ballot(kbr[0] < c)) + __popcll(__ballot(kbr[1] < c)) +
         __popcll(__ballot(kbr[2] < c)) + __popcll(__ballot(kbr[3] < c));
}

__global__ __launch_bounds__(256) void kselect(const float* __restrict__ s_ws,
                                               const unsigned short* __restrict__ lr_bf,
                                               unsigned* __restrict__ fm32,
                                               unsigned* __restrict__ fx32) {
  __shared__ float sT[4][256];
  __shared__ unsigned int lst[4][4][Kn];
  const int id = blockIdx.x;                 // 2048 blocks
  const int xcd = id & 7;
  const int rrx = id >> 3;
  const int b = xcd + 8 * (rrx & 15);        // all 16 seg-blocks of b on one XCD
  const int seg = rrx >> 4;                  // 0..15 (16 rows each)
  const int t = threadIdx.x, lane = t & 63, w = t >> 6;

  {
    const float* sb = s_ws + b * 1024;
    sT[0][t] = sb[t]; sT[1][t] = sb[256 + t];
    sT[2][t] = sb[512 + t]; sT[3][t] = sb[768 + t];
  }
  __syncthreads();

  float sj[4][4];
#pragma unroll
  for (int q = 0; q < 4; ++q)
#pragma unroll
    for (int c = 0; c < 4; ++c) sj[q][c] = sT[c][q * 64 + lane];

  const float C = -14.4269504088896340736f;  // -10 * log2(e)
  unsigned kb[4][4];
#pragma unroll
  for (int r = 0; r < 4; ++r) {
    const int i = seg * 16 + w * 4 + r;
    const float si0 = sT[0][i], si1 = sT[1][i], si2 = sT[2][i], si3 = sT[3][i];
#pragma unroll
    for (int q = 0; q < 4; ++q) {
      float d0 = sj[q][0] - si0;
      float d1 = sj[q][1] - si1;
      float d2_ = sj[q][2] - si2;
      float d3 = sj[q][3] - si3;
      float dd = ((d0 * d0 + d1 * d1) + d2_ * d2_) + d3 * d3;
      kb[r][q] = __float_as_uint(dd);  // d2 >= 0 -> order-preserving bits
    }
  }
  // 4-row-batched exact Kth-smallest bit search
  unsigned T[4] = {0u, 0u, 0u, 0u};
#pragma unroll 1
  for (int bit = 30; bit >= 0; --bit) {
    const unsigned m = 1u << bit;
    unsigned c0 = T[0] | m, c1 = T[1] | m, c2 = T[2] | m, c3 = T[3] | m;
    int n0 = cntlt(kb[0], c0);
    int n1 = cntlt(kb[1], c1);
    int n2 = cntlt(kb[2], c2);
    int n3 = cntlt(kb[3], c3);
    T[0] = (n0 < Kn) ? c0 : T[0];
    T[1] = (n1 < Kn) ? c1 : T[1];
    T[2] = (n2 < Kn) ? c2 : T[2];
    T[3] = (n3 < Kn) ? c3 : T[3];
  }
  // selection scatter (ties ascending-j -> matches stable top_k); v recomputed
#pragma unroll
  for (int r = 0; r < 4; ++r) {
    const unsigned Tr = T[r];
    int nlt = cntlt(kb[r], Tr);
    int rem = Kn - nlt;
    int base = 0, ecum = 0;
#pragma unroll
    for (int q = 0; q < 4; ++q) {
      bool lt = kb[r][q] < Tr;
      bool eq = kb[r][q] == Tr;
      unsigned long long meq = __ballot(eq);
      int eqrank = ecum + mbcnt64(meq);
      bool sel = lt || (eq && (eqrank < rem));
      unsigned long long msel = __ballot(sel);
      int pos = base + mbcnt64(msel);
      float v = exp2f(C * __uint_as_float(kb[r][q]));
      if (sel)
        lst[w][r][pos] = (__float_as_uint(v) & 0xFFFFFF00u) | (unsigned)(q * 64 + lane);
      base += __popcll(msel);
      ecum += __popcll(meq);
    }
  }
  // gather: half-wave = row-in-pair, lane&31 = feature pair; both pairs
  // interleaved in one loop for 2x load streams in flight.
  const int h = lane >> 5;
  const int f2 = lane & 31;
  const unsigned short* lrb = lr_bf + (size_t)b * (256 * NLRn);
  float am0[2] = {0.f, 0.f}, am1[2] = {0.f, 0.f};
  float ax0[2] = {0.f, 0.f}, ax1[2] = {0.f, 0.f};
#pragma unroll 4
  for (int tt = 0; tt < Kn; ++tt) {
#pragma unroll
    for (int p = 0; p < 2; ++p) {
      unsigned pk = lst[w][2 * p + h][tt];  // same addr per half-wave -> broadcast
      float v = __uint_as_float(pk & 0xFFFFFF00u);
      unsigned pr = *(const unsigned*)(lrb + ((pk & 0xFFu) << 6) + f2 * 2);
      float l0 = __uint_as_float(pr << 16);
      float l1 = __uint_as_float(pr & 0xFFFF0000u);
      float t0 = v * l0, t1 = v * l1;
      am0[p] += t0; am1[p] += t1;
      ax0[p] = fmaxf(ax0[p], t0); ax1[p] = fmaxf(ax1[p], t1);
    }
  }
#pragma unroll
  for (int p = 0; p < 2; ++p) {
    const int i = seg * 16 + w * 4 + 2 * p + h;
    size_t ro = ((size_t)(b * 256 + i)) * 32 + f2;  // u32 units
    float m0 = am0[p] * (1.f / 40.f), m1 = am1[p] * (1.f / 40.f);
    fm32[ro] = (unsigned)rneb(m0) | ((unsigned)rneb(m1) << 16);
    fx32[ro] = (unsigned)rneb(ax0[p]) | ((unsigned)rneb(ax1[p]) << 16);
  }
}

extern "C" void kernel_launch(void* const* d_in, const int* in_sizes, int n_in,
                              void* d_out, int out_size, void* d_ws, size_t ws_size,
                              hipStream_t stream) {
  const float* x = (const float*)d_in[0];
  const float* W_slr = (const float*)d_in[1];
  const float* b_slr = (const float*)d_in[2];
  const float* W_out = (const float*)d_in[3];
  const float* b_out = (const float*)d_in[4];
  float* out = (float*)d_out;

  char* p = (char*)d_ws;
  auto take = [&](size_t bytes) { char* c = p; p += (bytes + 255) & ~(size_t)255; return c; };
  short* xhi = (short*)take((size_t)ROWS * 64 * 2);
  short* wt1 = (short*)take(64 * 64 * 2);
  short* wt2 = (short*)take(128 * KB2 * 2);
  float* bias1lr = (float*)take(Bn * 64 * 4);
  float* bias2 = (float*)take(Bn * 128 * 4);
  float* s_ws = (float*)take(Bn * 1024 * 4);
  unsigned short* lr_bf = (unsigned short*)take((size_t)ROWS * 64 * 2);
  short* fm = (short*)take((size_t)ROWS * 64 * 2);
  short* fx = (short*)take((size_t)ROWS * 64 * 2);

  kprep<<<256, 256, 0, stream>>>(x, W_slr, b_slr, W_out, b_out,
                                 xhi, wt1, wt2, bias1lr, bias2, s_ws);
  kgemm1<<<ROWS / 64, 256, 0, stream>>>(xhi, wt1, bias1lr, lr_bf);
  kselect<<<Bn * 16, 256, 0, stream>>>(s_ws, lr_bf, (unsigned*)fm, (unsigned*)fx);
  kgemm2<<<ROWS / 64, 256, 0, stream>>>(xhi, fm, fx, wt2, bias2, out);
}